// Round 1
// baseline (11812.741 us; speedup 1.0000x reference)
//
#include <hip/hip_runtime.h>
#include <math.h>

#define BATCH 2
#define LSEQ  2048
#define EMB   2048
#define NH    16
#define HD    128

// ---------------------------------------------------------------------------
// GEMM: C[m,n] = sum_k A[m,k] * B[n,k]    (A: MxK row-major, B: NxK row-major)
// mode 0: write C row-major [M,N]
// mode 1: scatter into q/k/v buffers laid out [B, H, L, HD]
// ---------------------------------------------------------------------------
#define BM 128
#define BN 128
#define BK 16

__global__ __launch_bounds__(256) void gemm_nt(
    const float* __restrict__ A, const float* __restrict__ Bmat,
    float* __restrict__ C,
    float* __restrict__ qo, float* __restrict__ ko, float* __restrict__ vo,
    int M, int N, int K, int mode)
{
    __shared__ float As[BK][BM + 4];
    __shared__ float Bs[BK][BN + 4];

    const int tid = threadIdx.x;
    const int bm = blockIdx.y * BM;
    const int bn = blockIdx.x * BN;
    const int tx = tid & 15;
    const int ty = tid >> 4;
    const int arow = tid >> 2;        // 0..63
    const int ak   = (tid & 3) << 2;  // 0,4,8,12

    const float* Aptr = A + (size_t)(bm + arow) * K + ak;
    const float* Bptr = Bmat + (size_t)(bn + arow) * K + ak;

    float4 a0 = *(const float4*)(Aptr);
    float4 a1 = *(const float4*)(Aptr + (size_t)64 * K);
    float4 b0 = *(const float4*)(Bptr);
    float4 b1 = *(const float4*)(Bptr + (size_t)64 * K);

    float acc[8][8];
#pragma unroll
    for (int i = 0; i < 8; i++)
#pragma unroll
        for (int j = 0; j < 8; j++) acc[i][j] = 0.f;

    for (int k0 = 0; k0 < K; k0 += BK) {
        __syncthreads();
        As[ak + 0][arow] = a0.x; As[ak + 1][arow] = a0.y;
        As[ak + 2][arow] = a0.z; As[ak + 3][arow] = a0.w;
        As[ak + 0][arow + 64] = a1.x; As[ak + 1][arow + 64] = a1.y;
        As[ak + 2][arow + 64] = a1.z; As[ak + 3][arow + 64] = a1.w;
        Bs[ak + 0][arow] = b0.x; Bs[ak + 1][arow] = b0.y;
        Bs[ak + 2][arow] = b0.z; Bs[ak + 3][arow] = b0.w;
        Bs[ak + 0][arow + 64] = b1.x; Bs[ak + 1][arow + 64] = b1.y;
        Bs[ak + 2][arow + 64] = b1.z; Bs[ak + 3][arow + 64] = b1.w;
        __syncthreads();

        if (k0 + BK < K) {
            a0 = *(const float4*)(Aptr + k0 + BK);
            a1 = *(const float4*)(Aptr + (size_t)64 * K + k0 + BK);
            b0 = *(const float4*)(Bptr + k0 + BK);
            b1 = *(const float4*)(Bptr + (size_t)64 * K + k0 + BK);
        }

#pragma unroll
        for (int kk = 0; kk < BK; kk++) {
            float4 alo = *(const float4*)&As[kk][ty * 4];
            float4 ahi = *(const float4*)&As[kk][ty * 4 + 64];
            float4 blo = *(const float4*)&Bs[kk][tx * 4];
            float4 bhi = *(const float4*)&Bs[kk][tx * 4 + 64];
            float av[8] = {alo.x, alo.y, alo.z, alo.w, ahi.x, ahi.y, ahi.z, ahi.w};
            float bv[8] = {blo.x, blo.y, blo.z, blo.w, bhi.x, bhi.y, bhi.z, bhi.w};
#pragma unroll
            for (int i = 0; i < 8; i++)
#pragma unroll
                for (int j = 0; j < 8; j++)
                    acc[i][j] = fmaf(av[i], bv[j], acc[i][j]);
        }
    }

    // epilogue
#pragma unroll
    for (int i = 0; i < 8; i++) {
        const int ri = (i < 4) ? (ty * 4 + i) : (ty * 4 + 64 + (i - 4));
        const int m = bm + ri;
#pragma unroll
        for (int jg = 0; jg < 2; jg++) {
            const int n0 = bn + tx * 4 + jg * 64;
            float4 val;
            val.x = acc[i][jg * 4 + 0];
            val.y = acc[i][jg * 4 + 1];
            val.z = acc[i][jg * 4 + 2];
            val.w = acc[i][jg * 4 + 3];
            if (mode == 0) {
                *(float4*)(C + (size_t)m * N + n0) = val;
            } else {
                const int b = m >> 11;       // m / LSEQ
                const int l = m & 2047;
                const int which = n0 >> 11;  // 0=q 1=k 2=v
                const int e = n0 & 2047;
                const int h = e >> 7;
                const int d = e & 127;
                float* dst = (which == 0) ? qo : (which == 1) ? ko : vo;
                *(float4*)(dst + (((size_t)(b * NH + h)) * LSEQ + l) * HD + d) = val;
            }
        }
    }
}

// ---------------------------------------------------------------------------
// RoPE in-place on q and k, layout [B,H,L,HD]; rope: [L, HD/2, 2] (sin, cos)
// ---------------------------------------------------------------------------
__global__ __launch_bounds__(256) void rope_kernel(
    float* __restrict__ q, float* __restrict__ k,
    const float* __restrict__ rope, int pairs_per_tensor)
{
    int i = blockIdx.x * blockDim.x + threadIdx.x;
    if (i >= 2 * pairs_per_tensor) return;
    float* p = (i < pairs_per_tensor) ? q : k;
    int j = (i < pairs_per_tensor) ? i : (i - pairs_per_tensor);
    const int d2 = j & 63;                 // HD/2 = 64
    const int l = (j >> 6) & (LSEQ - 1);
    const size_t off = ((size_t)(j >> 6)) * HD + d2 * 2;
    const float sn = rope[l * HD + d2 * 2 + 0];
    const float cs = rope[l * HD + d2 * 2 + 1];
    const float x0 = p[off + 0];
    const float x1 = p[off + 1];
    p[off + 0] = x0 * cs - x1 * sn;
    p[off + 1] = x1 * cs + x0 * sn;
}

// ---------------------------------------------------------------------------
// Flash-style causal attention.
// q,k,v: [B*H, L, HD].  y out: [B, L, H, HD] (== [B,L,E] row-major).
// Block: 256 threads handles TQ=64 queries of one head; iterates TK=32 key tiles.
// ---------------------------------------------------------------------------
#define TQ 64
#define TK 32

__global__ __launch_bounds__(256) void attn_kernel(
    const float* __restrict__ q, const float* __restrict__ k,
    const float* __restrict__ v, float* __restrict__ y)
{
    __shared__ float Qs[TQ][HD + 4];    // 64 x 132
    __shared__ float KVs[TK][HD + 4];   // 32 x 132
    __shared__ float Ss[TQ][TK + 1];    // 64 x 33
    __shared__ float m_s[TQ], l_s[TQ], al_s[TQ];

    const int tid = threadIdx.x;
    const int qt = blockIdx.x;
    const int bh = blockIdx.y;
    const int q0 = qt * TQ;
    const size_t base = (size_t)bh * LSEQ * HD;
    const float scale = 0.08838834764831845f;  // 1/sqrt(128)

    const int rb = tid >> 5;   // 0..7  (O row base)
    const int c4 = tid & 31;   // O col group (float4)
    const int tr = tid & 15;   // S row base
    const int tc = tid >> 4;   // S col base

    // load Q tile
#pragma unroll
    for (int i = 0; i < 8; i++) {
        const int row = rb + i * 8;
        *(float4*)&Qs[row][c4 * 4] =
            *(const float4*)(q + base + (size_t)(q0 + row) * HD + c4 * 4);
    }
    if (tid < TQ) { m_s[tid] = -1e30f; l_s[tid] = 0.f; }

    float o[8][4];
#pragma unroll
    for (int i = 0; i < 8; i++)
#pragma unroll
        for (int j = 0; j < 4; j++) o[i][j] = 0.f;

    const int nkt = 2 * qt + 2;
    __syncthreads();

    for (int kt = 0; kt < nkt; kt++) {
        const int k0 = kt * TK;

        __syncthreads();  // (A) previous PV reads of KVs done
        // load K tile
#pragma unroll
        for (int i = 0; i < 4; i++) {
            const int row = rb + i * 8;
            *(float4*)&KVs[row][c4 * 4] =
                *(const float4*)(k + base + (size_t)(k0 + row) * HD + c4 * 4);
        }
        __syncthreads();  // (B) K ready

        // S = scale * Q K^T  (4 rows x 2 cols per thread)
        float s[4][2];
#pragma unroll
        for (int i = 0; i < 4; i++) { s[i][0] = 0.f; s[i][1] = 0.f; }
#pragma unroll
        for (int d4 = 0; d4 < HD / 4; d4++) {
            float4 qv[4], kv[2];
#pragma unroll
            for (int i = 0; i < 4; i++) qv[i] = *(const float4*)&Qs[tr + 16 * i][d4 * 4];
#pragma unroll
            for (int j = 0; j < 2; j++) kv[j] = *(const float4*)&KVs[tc + 16 * j][d4 * 4];
#pragma unroll
            for (int i = 0; i < 4; i++)
#pragma unroll
                for (int j = 0; j < 2; j++) {
                    s[i][j] = fmaf(qv[i].x, kv[j].x, s[i][j]);
                    s[i][j] = fmaf(qv[i].y, kv[j].y, s[i][j]);
                    s[i][j] = fmaf(qv[i].z, kv[j].z, s[i][j]);
                    s[i][j] = fmaf(qv[i].w, kv[j].w, s[i][j]);
                }
        }
#pragma unroll
        for (int i = 0; i < 4; i++)
#pragma unroll
            for (int j = 0; j < 2; j++) {
                const int r = tr + 16 * i;
                const int c = tc + 16 * j;
                Ss[r][c] = (k0 + c <= q0 + r) ? s[i][j] * scale : -1e30f;
            }
        __syncthreads();  // (C) Ss ready; K reads done

        // online-softmax row update
        if (tid < TQ) {
            const int r = tid;
            const float mo = m_s[r];
            float mx = mo;
#pragma unroll
            for (int c = 0; c < TK; c++) mx = fmaxf(mx, Ss[r][c]);
            const float al = __expf(mo - mx);
            float sum = 0.f;
#pragma unroll
            for (int c = 0; c < TK; c++) {
                const float p = __expf(Ss[r][c] - mx);
                Ss[r][c] = p;
                sum += p;
            }
            m_s[r] = mx;
            l_s[r] = l_s[r] * al + sum;
            al_s[r] = al;
        }
        // load V tile (KVs free after (C))
#pragma unroll
        for (int i = 0; i < 4; i++) {
            const int row = rb + i * 8;
            *(float4*)&KVs[row][c4 * 4] =
                *(const float4*)(v + base + (size_t)(k0 + row) * HD + c4 * 4);
        }
        __syncthreads();  // (D) P, alpha, V ready

        // O = O*alpha + P V
#pragma unroll
        for (int i = 0; i < 8; i++) {
            const float a_i = al_s[rb + 8 * i];
#pragma unroll
            for (int j = 0; j < 4; j++) o[i][j] *= a_i;
        }
#pragma unroll
        for (int c = 0; c < TK; c++) {
            const float4 vv = *(const float4*)&KVs[c][c4 * 4];
#pragma unroll
            for (int i = 0; i < 8; i++) {
                const float p = Ss[rb + 8 * i][c];
                o[i][0] = fmaf(p, vv.x, o[i][0]);
                o[i][1] = fmaf(p, vv.y, o[i][1]);
                o[i][2] = fmaf(p, vv.z, o[i][2]);
                o[i][3] = fmaf(p, vv.w, o[i][3]);
            }
        }
    }

    // epilogue: normalize and write y[B, L, H, HD]
    const int b = bh / NH;
    const int h = bh % NH;
#pragma unroll
    for (int i = 0; i < 8; i++) {
        const int r = rb + 8 * i;
        const float inv = 1.f / l_s[r];
        float4 ov;
        ov.x = o[i][0] * inv; ov.y = o[i][1] * inv;
        ov.z = o[i][2] * inv; ov.w = o[i][3] * inv;
        *(float4*)(y + (((size_t)b * LSEQ + q0 + r) * NH + h) * HD + c4 * 4) = ov;
    }
}

// ---------------------------------------------------------------------------
extern "C" void kernel_launch(void* const* d_in, const int* in_sizes, int n_in,
                              void* d_out, int out_size, void* d_ws, size_t ws_size,
                              hipStream_t stream) {
    const float* x      = (const float*)d_in[0];
    const float* rope   = (const float*)d_in[1];
    const float* w_attn = (const float*)d_in[2];
    const float* w_proj = (const float*)d_in[3];
    float* out = (float*)d_out;
    float* ws  = (float*)d_ws;

    const size_t per = (size_t)BATCH * NH * LSEQ * HD;  // 8,388,608 floats
    float* qb = ws;
    float* kb = ws + per;
    float* vb = ws + 2 * per;
    float* yb = ws + 3 * per;

    const int M = BATCH * LSEQ;  // 4096

    // 1) QKV projection, scattered into [B,H,L,HD] buffers
    dim3 g1(3 * EMB / BN, M / BM);  // (48, 32)
    gemm_nt<<<g1, 256, 0, stream>>>(x, w_attn, nullptr, qb, kb, vb, M, 3 * EMB, EMB, 1);

    // 2) RoPE in-place on q, k
    const int pairs = (int)(per / 2);  // 4,194,304 per tensor
    rope_kernel<<<(2 * pairs + 255) / 256, 256, 0, stream>>>(qb, kb, rope, pairs);

    // 3) causal flash attention -> y [B,L,H,HD]
    dim3 ga(LSEQ / TQ, BATCH * NH);  // (32, 32)
    attn_kernel<<<ga, 256, 0, stream>>>(qb, kb, vb, yb);

    // 4) output projection
    dim3 g2(EMB / BN, M / BM);  // (16, 32)
    gemm_nt<<<g2, 256, 0, stream>>>(yb, w_proj, out, nullptr, nullptr, nullptr, M, EMB, EMB, 0);
}

// Round 2
// 2105.852 us; speedup vs baseline: 5.6095x; 5.6095x over previous
//
#include <hip/hip_runtime.h>
#include <math.h>

#define BATCH 2
#define LSEQ  2048
#define EMB   2048
#define NH    16
#define HD    128

typedef __attribute__((ext_vector_type(8))) short bf16x8;
typedef __attribute__((ext_vector_type(4))) float f32x4;

static __device__ __forceinline__ unsigned short f2bf(float f) {
    unsigned u = __float_as_uint(f);
    u += 0x7fffu + ((u >> 16) & 1u);
    return (unsigned short)(u >> 16);
}

// ---------------------------------------------------------------------------
// GEMM: C[m,n] = sum_k A[m,k] * B[n,k]    (A: MxK row-major, B: NxK row-major)
// mode 0: write C row-major [M,N]
// mode 1: scatter into q/k/v buffers laid out [B, H, L, HD]
// ---------------------------------------------------------------------------
#define BM 128
#define BN 128
#define BK 16

__global__ __launch_bounds__(256) void gemm_nt(
    const float* __restrict__ A, const float* __restrict__ Bmat,
    float* __restrict__ C,
    float* __restrict__ qo, float* __restrict__ ko, float* __restrict__ vo,
    int M, int N, int K, int mode)
{
    __shared__ float As[BK][BM + 4];
    __shared__ float Bs[BK][BN + 4];

    const int tid = threadIdx.x;
    const int bm = blockIdx.y * BM;
    const int bn = blockIdx.x * BN;
    const int tx = tid & 15;
    const int ty = tid >> 4;
    const int arow = tid >> 2;        // 0..63
    const int ak   = (tid & 3) << 2;  // 0,4,8,12

    const float* Aptr = A + (size_t)(bm + arow) * K + ak;
    const float* Bptr = Bmat + (size_t)(bn + arow) * K + ak;

    float4 a0 = *(const float4*)(Aptr);
    float4 a1 = *(const float4*)(Aptr + (size_t)64 * K);
    float4 b0 = *(const float4*)(Bptr);
    float4 b1 = *(const float4*)(Bptr + (size_t)64 * K);

    float acc[8][8];
#pragma unroll
    for (int i = 0; i < 8; i++)
#pragma unroll
        for (int j = 0; j < 8; j++) acc[i][j] = 0.f;

    for (int k0 = 0; k0 < K; k0 += BK) {
        __syncthreads();
        As[ak + 0][arow] = a0.x; As[ak + 1][arow] = a0.y;
        As[ak + 2][arow] = a0.z; As[ak + 3][arow] = a0.w;
        As[ak + 0][arow + 64] = a1.x; As[ak + 1][arow + 64] = a1.y;
        As[ak + 2][arow + 64] = a1.z; As[ak + 3][arow + 64] = a1.w;
        Bs[ak + 0][arow] = b0.x; Bs[ak + 1][arow] = b0.y;
        Bs[ak + 2][arow] = b0.z; Bs[ak + 3][arow] = b0.w;
        Bs[ak + 0][arow + 64] = b1.x; Bs[ak + 1][arow + 64] = b1.y;
        Bs[ak + 2][arow + 64] = b1.z; Bs[ak + 3][arow + 64] = b1.w;
        __syncthreads();

        if (k0 + BK < K) {
            a0 = *(const float4*)(Aptr + k0 + BK);
            a1 = *(const float4*)(Aptr + (size_t)64 * K + k0 + BK);
            b0 = *(const float4*)(Bptr + k0 + BK);
            b1 = *(const float4*)(Bptr + (size_t)64 * K + k0 + BK);
        }

#pragma unroll
        for (int kk = 0; kk < BK; kk++) {
            float4 alo = *(const float4*)&As[kk][ty * 4];
            float4 ahi = *(const float4*)&As[kk][ty * 4 + 64];
            float4 blo = *(const float4*)&Bs[kk][tx * 4];
            float4 bhi = *(const float4*)&Bs[kk][tx * 4 + 64];
            float av[8] = {alo.x, alo.y, alo.z, alo.w, ahi.x, ahi.y, ahi.z, ahi.w};
            float bv[8] = {blo.x, blo.y, blo.z, blo.w, bhi.x, bhi.y, bhi.z, bhi.w};
#pragma unroll
            for (int i = 0; i < 8; i++)
#pragma unroll
                for (int j = 0; j < 8; j++)
                    acc[i][j] = fmaf(av[i], bv[j], acc[i][j]);
        }
    }

    // epilogue
#pragma unroll
    for (int i = 0; i < 8; i++) {
        const int ri = (i < 4) ? (ty * 4 + i) : (ty * 4 + 64 + (i - 4));
        const int m = bm + ri;
#pragma unroll
        for (int jg = 0; jg < 2; jg++) {
            const int n0 = bn + tx * 4 + jg * 64;
            float4 val;
            val.x = acc[i][jg * 4 + 0];
            val.y = acc[i][jg * 4 + 1];
            val.z = acc[i][jg * 4 + 2];
            val.w = acc[i][jg * 4 + 3];
            if (mode == 0) {
                *(float4*)(C + (size_t)m * N + n0) = val;
            } else {
                const int b = m >> 11;       // m / LSEQ
                const int l = m & 2047;
                const int which = n0 >> 11;  // 0=q 1=k 2=v
                const int e = n0 & 2047;
                const int h = e >> 7;
                const int d = e & 127;
                float* dst = (which == 0) ? qo : (which == 1) ? ko : vo;
                *(float4*)(dst + (((size_t)(b * NH + h)) * LSEQ + l) * HD + d) = val;
            }
        }
    }
}

// ---------------------------------------------------------------------------
// RoPE in-place on q and k, layout [B,H,L,HD]; rope: [L, HD/2, 2] (sin, cos)
// ---------------------------------------------------------------------------
__global__ __launch_bounds__(256) void rope_kernel(
    float* __restrict__ q, float* __restrict__ k,
    const float* __restrict__ rope, int pairs_per_tensor)
{
    int i = blockIdx.x * blockDim.x + threadIdx.x;
    if (i >= 2 * pairs_per_tensor) return;
    float* p = (i < pairs_per_tensor) ? q : k;
    int j = (i < pairs_per_tensor) ? i : (i - pairs_per_tensor);
    const int d2 = j & 63;                 // HD/2 = 64
    const int l = (j >> 6) & (LSEQ - 1);
    const size_t off = ((size_t)(j >> 6)) * HD + d2 * 2;
    const float sn = rope[l * HD + d2 * 2 + 0];
    const float cs = rope[l * HD + d2 * 2 + 1];
    const float x0 = p[off + 0];
    const float x1 = p[off + 1];
    p[off + 0] = x0 * cs - x1 * sn;
    p[off + 1] = x1 * cs + x0 * sn;
}

// ---------------------------------------------------------------------------
// MFMA bf16 flash attention (causal).
// q,k,v: [B*H, L, HD] fp32.  y out: [B, L, H, HD] fp32.
// Block: 256 threads (4 waves). TQ=64 queries/block (16/wave), TK=64 keys/tile.
// mfma_f32_16x16x32_bf16:
//   A frag: lane holds A[m=lane&15][k=(lane>>4)*8+j], j=0..7 (contiguous)
//   B frag: lane holds B[k=(lane>>4)*8+j][n=lane&15]
//   C/D   : col=lane&15, row=(lane>>4)*4+reg
// ---------------------------------------------------------------------------
#define TQ 64
#define TK 64
#define QS_STR 136   // ushort stride (272 B = 68 words; 4*(m+g)%32 uniform banks)
#define KS_STR 136
#define VT_STR 72    // 144 B = 36 words
#define PS_STR 72

__global__ __launch_bounds__(256) void attn_kernel(
    const float* __restrict__ q, const float* __restrict__ k,
    const float* __restrict__ v, float* __restrict__ y)
{
    __shared__ unsigned short Qs[TQ * QS_STR];   // 17408 B
    __shared__ unsigned short Ks[TK * KS_STR];   // 17408 B
    __shared__ unsigned short Vt[HD * VT_STR];   // 18432 B (V transposed: [d][key])
    __shared__ unsigned short Ps[TQ * PS_STR];   //  9216 B

    const int tid = threadIdx.x;
    const int lane = tid & 63;
    const int w = tid >> 6;        // wave id: rows w*16 .. w*16+15 (local)
    const int m = lane & 15;
    const int g = lane >> 4;
    const int qt = blockIdx.x;
    const int bh = blockIdx.y;
    const int q0 = qt * TQ;
    const size_t base = (size_t)bh * LSEQ * HD;
    const float scale = 0.08838834764831845f;  // 1/sqrt(128)

    // ---- load Q tile -> LDS bf16 ----
    {
        const int row = tid >> 2;
        const int c0 = (tid & 3) * 32;
        const float* src = q + base + (size_t)(q0 + row) * HD + c0;
        unsigned short* dst = &Qs[row * QS_STR + c0];
#pragma unroll
        for (int i = 0; i < 8; i++) {
            float4 f = *(const float4*)(src + i * 4);
            ushort4 u;
            u.x = f2bf(f.x); u.y = f2bf(f.y); u.z = f2bf(f.z); u.w = f2bf(f.w);
            *(ushort4*)(dst + i * 4) = u;
        }
    }

    f32x4 o[8];
#pragma unroll
    for (int i = 0; i < 8; i++) o[i] = (f32x4){0.f, 0.f, 0.f, 0.f};
    float mprev[4], lsum[4];
#pragma unroll
    for (int r = 0; r < 4; r++) { mprev[r] = -1e30f; lsum[r] = 0.f; }

    const int nkt = qt + 1;
    for (int kt = 0; kt < nkt; kt++) {
        const int k0 = kt * TK;
        __syncthreads();  // previous-iter LDS reads done
        // load K tile (row-major bf16)
        {
            const int row = tid >> 2;
            const int c0 = (tid & 3) * 32;
            const float* src = k + base + (size_t)(k0 + row) * HD + c0;
            unsigned short* dst = &Ks[row * KS_STR + c0];
#pragma unroll
            for (int i = 0; i < 8; i++) {
                float4 f = *(const float4*)(src + i * 4);
                ushort4 u;
                u.x = f2bf(f.x); u.y = f2bf(f.y); u.z = f2bf(f.z); u.w = f2bf(f.w);
                *(ushort4*)(dst + i * 4) = u;
            }
        }
        // load V tile transposed: Vt[d][key]
        {
            const int key = tid & 63;
            const int d0 = (tid >> 6) * 32;
            const float* src = v + base + (size_t)(k0 + key) * HD + d0;
#pragma unroll
            for (int i = 0; i < 8; i++) {
                float4 f = *(const float4*)(src + i * 4);
                const int d = d0 + i * 4;
                Vt[(d + 0) * VT_STR + key] = f2bf(f.x);
                Vt[(d + 1) * VT_STR + key] = f2bf(f.y);
                Vt[(d + 2) * VT_STR + key] = f2bf(f.z);
                Vt[(d + 3) * VT_STR + key] = f2bf(f.w);
            }
        }
        __syncthreads();

        // ---- S = Q K^T over this wave's 16 rows x 64 keys ----
        bf16x8 aq[4];
#pragma unroll
        for (int kc = 0; kc < 4; kc++)
            aq[kc] = *(const bf16x8*)&Qs[(w * 16 + m) * QS_STR + kc * 32 + g * 8];

        f32x4 s[4];
#pragma unroll
        for (int n = 0; n < 4; n++) {
            f32x4 acc = (f32x4){0.f, 0.f, 0.f, 0.f};
#pragma unroll
            for (int kc = 0; kc < 4; kc++) {
                bf16x8 bk = *(const bf16x8*)&Ks[(n * 16 + m) * KS_STR + kc * 32 + g * 8];
                acc = __builtin_amdgcn_mfma_f32_16x16x32_bf16(aq[kc], bk, acc, 0, 0, 0);
            }
            s[n] = acc;
        }

        // ---- scale + causal mask (row = q0+w*16+g*4+r, col = k0+n*16+m) ----
        const int rowg = q0 + w * 16 + g * 4;
#pragma unroll
        for (int n = 0; n < 4; n++) {
            const int col = k0 + n * 16 + m;
#pragma unroll
            for (int r = 0; r < 4; r++) {
                float val = s[n][r] * scale;
                s[n][r] = (col <= rowg + r) ? val : -1e30f;
            }
        }

        // ---- online softmax (row reductions across the 16-lane group) ----
        float al[4];
#pragma unroll
        for (int r = 0; r < 4; r++) {
            float v0 = fmaxf(fmaxf(s[0][r], s[1][r]), fmaxf(s[2][r], s[3][r]));
            v0 = fmaxf(v0, __shfl_xor(v0, 1));
            v0 = fmaxf(v0, __shfl_xor(v0, 2));
            v0 = fmaxf(v0, __shfl_xor(v0, 4));
            v0 = fmaxf(v0, __shfl_xor(v0, 8));
            const float mn = fmaxf(mprev[r], v0);
            al[r] = __expf(mprev[r] - mn);
            mprev[r] = mn;
        }
#pragma unroll
        for (int r = 0; r < 4; r++) {
            float sum = 0.f;
#pragma unroll
            for (int n = 0; n < 4; n++) {
                const float p = __expf(s[n][r] - mprev[r]);
                sum += p;
                Ps[(w * 16 + g * 4 + r) * PS_STR + n * 16 + m] = f2bf(p);
            }
            sum += __shfl_xor(sum, 1);
            sum += __shfl_xor(sum, 2);
            sum += __shfl_xor(sum, 4);
            sum += __shfl_xor(sum, 8);
            lsum[r] = lsum[r] * al[r] + sum;
        }

        // ---- O = O*alpha + P V ----
#pragma unroll
        for (int dc = 0; dc < 8; dc++)
#pragma unroll
            for (int r = 0; r < 4; r++) o[dc][r] *= al[r];

        // wave reads only its own Ps rows -> same-wave DS ordering suffices
        bf16x8 ap[2];
#pragma unroll
        for (int kk = 0; kk < 2; kk++)
            ap[kk] = *(const bf16x8*)&Ps[(w * 16 + m) * PS_STR + kk * 32 + g * 8];
#pragma unroll
        for (int dc = 0; dc < 8; dc++) {
#pragma unroll
            for (int kk = 0; kk < 2; kk++) {
                bf16x8 bv = *(const bf16x8*)&Vt[(dc * 16 + m) * VT_STR + kk * 32 + g * 8];
                o[dc] = __builtin_amdgcn_mfma_f32_16x16x32_bf16(ap[kk], bv, o[dc], 0, 0, 0);
            }
        }
    }

    // ---- epilogue: normalize, write y[B, L, H, HD] ----
    const int b = bh / NH;
    const int h = bh % NH;
#pragma unroll
    for (int r = 0; r < 4; r++) {
        const float inv = 1.f / lsum[r];
        const int lrow = q0 + w * 16 + g * 4 + r;
        float* dst = y + (((size_t)b * LSEQ + lrow) * NH + h) * HD;
#pragma unroll
        for (int dc = 0; dc < 8; dc++)
            dst[dc * 16 + m] = o[dc][r] * inv;
    }
}

// ---------------------------------------------------------------------------
extern "C" void kernel_launch(void* const* d_in, const int* in_sizes, int n_in,
                              void* d_out, int out_size, void* d_ws, size_t ws_size,
                              hipStream_t stream) {
    const float* x      = (const float*)d_in[0];
    const float* rope   = (const float*)d_in[1];
    const float* w_attn = (const float*)d_in[2];
    const float* w_proj = (const float*)d_in[3];
    float* out = (float*)d_out;
    float* ws  = (float*)d_ws;

    const size_t per = (size_t)BATCH * NH * LSEQ * HD;  // 8,388,608 floats
    float* qb = ws;
    float* kb = ws + per;
    float* vb = ws + 2 * per;
    float* yb = ws + 3 * per;

    const int M = BATCH * LSEQ;  // 4096

    // 1) QKV projection, scattered into [B,H,L,HD] buffers
    dim3 g1(3 * EMB / BN, M / BM);  // (48, 32)
    gemm_nt<<<g1, 256, 0, stream>>>(x, w_attn, nullptr, qb, kb, vb, M, 3 * EMB, EMB, 1);

    // 2) RoPE in-place on q, k
    const int pairs = (int)(per / 2);
    rope_kernel<<<(2 * pairs + 255) / 256, 256, 0, stream>>>(qb, kb, rope, pairs);

    // 3) causal flash attention (MFMA bf16) -> y [B,L,H,HD]
    dim3 ga(LSEQ / TQ, BATCH * NH);  // (32, 32)
    attn_kernel<<<ga, 256, 0, stream>>>(qb, kb, vb, yb);

    // 4) output projection
    dim3 g2(EMB / BN, M / BM);  // (16, 32)
    gemm_nt<<<g2, 256, 0, stream>>>(yb, w_proj, out, nullptr, nullptr, nullptr, M, EMB, EMB, 0);
}

// Round 3
// 553.376 us; speedup vs baseline: 21.3467x; 3.8055x over previous
//
#include <hip/hip_runtime.h>
#include <math.h>

#define BATCH 2
#define LSEQ  2048
#define EMB   2048
#define NH    16
#define HD    128

typedef __attribute__((ext_vector_type(8))) short bf16x8;
typedef __attribute__((ext_vector_type(8))) unsigned short u16x8;
typedef __attribute__((ext_vector_type(4))) float f32x4;

static __device__ __forceinline__ unsigned short f2bf(float f) {
    unsigned u = __float_as_uint(f);
    u += 0x7fffu + ((u >> 16) & 1u);
    return (unsigned short)(u >> 16);
}
static __device__ __forceinline__ float bf2f(unsigned short h) {
    return __uint_as_float(((unsigned)h) << 16);
}

// async global->LDS, 16 bytes per lane; LDS dest must be wave-uniform base + lane*16
static __device__ __forceinline__ void load_lds16(const void* g, void* l) {
    __builtin_amdgcn_global_load_lds(
        (const __attribute__((address_space(1))) void*)g,
        (__attribute__((address_space(3))) void*)l, 16, 0, 0);
}

// ---------------------------------------------------------------------------
// cast fp32 -> bf16 for x, w_attn, w_proj (one grid-stride-free flat kernel)
// ---------------------------------------------------------------------------
#define N1 (BATCH * LSEQ * EMB)      // 8388608  (x)
#define N2 (3 * EMB * EMB)           // 12582912 (w_attn)
#define N3 (EMB * EMB)               // 4194304  (w_proj)

__global__ __launch_bounds__(256) void cast_bf16_kernel(
    const float* __restrict__ x, const float* __restrict__ wa,
    const float* __restrict__ wp,
    unsigned short* __restrict__ xb, unsigned short* __restrict__ wab,
    unsigned short* __restrict__ wpb)
{
    size_t i4 = ((size_t)blockIdx.x * 256 + threadIdx.x) * 4;
    const float* src;
    unsigned short* dst;
    size_t off;
    if (i4 < (size_t)N1) { src = x; dst = xb; off = i4; }
    else if (i4 < (size_t)N1 + N2) { src = wa; dst = wab; off = i4 - N1; }
    else { src = wp; dst = wpb; off = i4 - N1 - N2; }
    float4 f = *(const float4*)(src + off);
    ushort4 u;
    u.x = f2bf(f.x); u.y = f2bf(f.y); u.z = f2bf(f.z); u.w = f2bf(f.w);
    *(ushort4*)(dst + off) = u;
}

// ---------------------------------------------------------------------------
// MFMA bf16 GEMM: C[m,n] = sum_k A[m,k]*B[n,k]  (A MxK, B NxK, both row-major bf16)
// m97 structure: 128x128 tile, 4 waves, 4x4 acc/wave, BK=64, global_load_lds(16B).
// mode 0: C fp32 row-major [M,N]
// mode 1: scatter bf16 into q/k/v buffers laid out [B,H,L,HD]
// ---------------------------------------------------------------------------
__global__ __launch_bounds__(256) void gemm_bt_bf16(
    const unsigned short* __restrict__ A, const unsigned short* __restrict__ B,
    float* __restrict__ C,
    unsigned short* __restrict__ qo, unsigned short* __restrict__ ko,
    unsigned short* __restrict__ vo,
    int M, int N, int K, int mode)
{
    __shared__ unsigned short As[128 * 64];  // 16 KB
    __shared__ unsigned short Bs[128 * 64];  // 16 KB

    const int tid = threadIdx.x;
    const int lane = tid & 63;
    const int w = tid >> 6;
    const int m = lane & 15;
    const int g = lane >> 4;
    const int wm = (w & 1) * 64;
    const int wn = (w >> 1) * 64;
    const int bm = blockIdx.y * 128;
    const int bn = blockIdx.x * 128;

    // staging map: chunk = i*256 + tid; row = chunk>>3; col8 = (chunk&7)*8
    const int srow = tid >> 3;
    const int scol = (tid & 7) * 8;

    f32x4 acc[4][4];
#pragma unroll
    for (int mi = 0; mi < 4; mi++)
#pragma unroll
        for (int ni = 0; ni < 4; ni++) acc[mi][ni] = (f32x4){0.f, 0.f, 0.f, 0.f};

    for (int k0 = 0; k0 < K; k0 += 64) {
        __syncthreads();
#pragma unroll
        for (int i = 0; i < 4; i++) {
            const int row = i * 32 + srow;
            load_lds16(A + (size_t)(bm + row) * K + k0 + scol, &As[row * 64 + scol]);
            load_lds16(B + (size_t)(bn + row) * K + k0 + scol, &Bs[row * 64 + scol]);
        }
        __syncthreads();

#pragma unroll
        for (int kc = 0; kc < 2; kc++) {
            bf16x8 af[4], bfv[4];
#pragma unroll
            for (int mi = 0; mi < 4; mi++)
                af[mi] = *(const bf16x8*)&As[(wm + mi * 16 + m) * 64 + kc * 32 + g * 8];
#pragma unroll
            for (int ni = 0; ni < 4; ni++)
                bfv[ni] = *(const bf16x8*)&Bs[(wn + ni * 16 + m) * 64 + kc * 32 + g * 8];
#pragma unroll
            for (int mi = 0; mi < 4; mi++)
#pragma unroll
                for (int ni = 0; ni < 4; ni++)
                    acc[mi][ni] = __builtin_amdgcn_mfma_f32_16x16x32_bf16(
                        af[mi], bfv[ni], acc[mi][ni], 0, 0, 0);
        }
    }

    // epilogue: C/D layout col=lane&15, row=g*4+reg
#pragma unroll
    for (int mi = 0; mi < 4; mi++) {
#pragma unroll
        for (int ni = 0; ni < 4; ni++) {
            const int col = bn + wn + ni * 16 + m;
#pragma unroll
            for (int r = 0; r < 4; r++) {
                const int row = bm + wm + mi * 16 + g * 4 + r;
                const float val = acc[mi][ni][r];
                if (mode == 0) {
                    C[(size_t)row * N + col] = val;
                } else {
                    const int b = row >> 11;
                    const int l = row & 2047;
                    const int which = col >> 11;
                    const int e = col & 2047;
                    const int h = e >> 7;
                    const int d = e & 127;
                    unsigned short* dst = (which == 0) ? qo : (which == 1) ? ko : vo;
                    dst[(((size_t)(b * NH + h)) * LSEQ + l) * HD + d] = f2bf(val);
                }
            }
        }
    }
}

// ---------------------------------------------------------------------------
// RoPE in-place on bf16 q and k, layout [B,H,L,HD]; rope: [L, HD/2, 2] (sin,cos)
// Each thread: 8 consecutive bf16 (4 rotation pairs).
// ---------------------------------------------------------------------------
#define NT8 (BATCH * NH * LSEQ * HD / 8)  // 1048576 per tensor

__global__ __launch_bounds__(256) void rope_kernel(
    unsigned short* __restrict__ q, unsigned short* __restrict__ k,
    const float* __restrict__ rope)
{
    const int i = blockIdx.x * 256 + threadIdx.x;
    unsigned short* p = (i < NT8) ? q : k;
    const int j = (i < NT8) ? i : (i - NT8);
    const int o8 = j & 15;              // 16 groups of 8 per 128-wide row
    const int l = (j >> 4) & (LSEQ - 1);
    const size_t off = (size_t)j * 8;
    u16x8 u = *(const u16x8*)(p + off);
    const float* rp = rope + l * HD + o8 * 8;  // 4 (sin,cos) pairs, contiguous
    u16x8 o;
#pragma unroll
    for (int t = 0; t < 4; t++) {
        const float sn = rp[t * 2 + 0];
        const float cs = rp[t * 2 + 1];
        const float x0 = bf2f(u[t * 2 + 0]);
        const float x1 = bf2f(u[t * 2 + 1]);
        o[t * 2 + 0] = f2bf(x0 * cs - x1 * sn);
        o[t * 2 + 1] = f2bf(x1 * cs + x0 * sn);
    }
    *(u16x8*)(p + off) = o;
}

// ---------------------------------------------------------------------------
// MFMA bf16 flash attention (causal).
// q,k,v: [B*H, L, HD] bf16.  y out: [B, L, H, HD] bf16.
// ---------------------------------------------------------------------------
#define TQ 64
#define TK 64
#define QS_STR 136
#define KS_STR 136
#define VT_STR 72
#define PS_STR 72

__global__ __launch_bounds__(256) void attn_kernel(
    const unsigned short* __restrict__ q, const unsigned short* __restrict__ k,
    const unsigned short* __restrict__ v, unsigned short* __restrict__ y)
{
    __shared__ unsigned short Qs[TQ * QS_STR];
    __shared__ unsigned short Ks[TK * KS_STR];
    __shared__ unsigned short Vt[HD * VT_STR];   // V transposed: [d][key]
    __shared__ unsigned short Ps[TQ * PS_STR];

    const int tid = threadIdx.x;
    const int lane = tid & 63;
    const int w = tid >> 6;
    const int m = lane & 15;
    const int g = lane >> 4;
    const int qt = blockIdx.x;
    const int bh = blockIdx.y;
    const int q0 = qt * TQ;
    const size_t base = (size_t)bh * LSEQ * HD;
    const float scale = 0.08838834764831845f;  // 1/sqrt(128)

    // ---- load Q tile -> LDS ----
    {
        const int row = tid >> 2;
        const int c0 = (tid & 3) * 32;
        const unsigned short* src = q + base + (size_t)(q0 + row) * HD + c0;
        unsigned short* dst = &Qs[row * QS_STR + c0];
#pragma unroll
        for (int i = 0; i < 4; i++)
            *(u16x8*)(dst + i * 8) = *(const u16x8*)(src + i * 8);
    }

    f32x4 o[8];
#pragma unroll
    for (int i = 0; i < 8; i++) o[i] = (f32x4){0.f, 0.f, 0.f, 0.f};
    float mprev[4], lsum[4];
#pragma unroll
    for (int r = 0; r < 4; r++) { mprev[r] = -1e30f; lsum[r] = 0.f; }

    const int nkt = qt + 1;
    for (int kt = 0; kt < nkt; kt++) {
        const int k0 = kt * TK;
        __syncthreads();
        // K tile (row-major)
        {
            const int row = tid >> 2;
            const int c0 = (tid & 3) * 32;
            const unsigned short* src = k + base + (size_t)(k0 + row) * HD + c0;
            unsigned short* dst = &Ks[row * KS_STR + c0];
#pragma unroll
            for (int i = 0; i < 4; i++)
                *(u16x8*)(dst + i * 8) = *(const u16x8*)(src + i * 8);
        }
        // V tile transposed
        {
            const int key = tid & 63;
            const int d0 = (tid >> 6) * 32;
            const unsigned short* src = v + base + (size_t)(k0 + key) * HD + d0;
#pragma unroll
            for (int i = 0; i < 4; i++) {
                u16x8 u = *(const u16x8*)(src + i * 8);
#pragma unroll
                for (int t = 0; t < 8; t++)
                    Vt[(d0 + i * 8 + t) * VT_STR + key] = u[t];
            }
        }
        __syncthreads();

        // ---- S = Q K^T ----
        bf16x8 aq[4];
#pragma unroll
        for (int kc = 0; kc < 4; kc++)
            aq[kc] = *(const bf16x8*)&Qs[(w * 16 + m) * QS_STR + kc * 32 + g * 8];

        f32x4 s[4];
#pragma unroll
        for (int n = 0; n < 4; n++) {
            f32x4 acc = (f32x4){0.f, 0.f, 0.f, 0.f};
#pragma unroll
            for (int kc = 0; kc < 4; kc++) {
                bf16x8 bk = *(const bf16x8*)&Ks[(n * 16 + m) * KS_STR + kc * 32 + g * 8];
                acc = __builtin_amdgcn_mfma_f32_16x16x32_bf16(aq[kc], bk, acc, 0, 0, 0);
            }
            s[n] = acc;
        }

        // ---- scale + causal mask ----
        const int rowg = q0 + w * 16 + g * 4;
#pragma unroll
        for (int n = 0; n < 4; n++) {
            const int col = k0 + n * 16 + m;
#pragma unroll
            for (int r = 0; r < 4; r++) {
                float val = s[n][r] * scale;
                s[n][r] = (col <= rowg + r) ? val : -1e30f;
            }
        }

        // ---- online softmax ----
        float al[4];
#pragma unroll
        for (int r = 0; r < 4; r++) {
            float v0 = fmaxf(fmaxf(s[0][r], s[1][r]), fmaxf(s[2][r], s[3][r]));
            v0 = fmaxf(v0, __shfl_xor(v0, 1));
            v0 = fmaxf(v0, __shfl_xor(v0, 2));
            v0 = fmaxf(v0, __shfl_xor(v0, 4));
            v0 = fmaxf(v0, __shfl_xor(v0, 8));
            const float mn = fmaxf(mprev[r], v0);
            al[r] = __expf(mprev[r] - mn);
            mprev[r] = mn;
        }
#pragma unroll
        for (int r = 0; r < 4; r++) {
            float sum = 0.f;
#pragma unroll
            for (int n = 0; n < 4; n++) {
                const float p = __expf(s[n][r] - mprev[r]);
                sum += p;
                Ps[(w * 16 + g * 4 + r) * PS_STR + n * 16 + m] = f2bf(p);
            }
            sum += __shfl_xor(sum, 1);
            sum += __shfl_xor(sum, 2);
            sum += __shfl_xor(sum, 4);
            sum += __shfl_xor(sum, 8);
            lsum[r] = lsum[r] * al[r] + sum;
        }

        // ---- O = O*alpha + P V ----
#pragma unroll
        for (int dc = 0; dc < 8; dc++)
#pragma unroll
            for (int r = 0; r < 4; r++) o[dc][r] *= al[r];

        bf16x8 ap[2];
#pragma unroll
        for (int kk = 0; kk < 2; kk++)
            ap[kk] = *(const bf16x8*)&Ps[(w * 16 + m) * PS_STR + kk * 32 + g * 8];
#pragma unroll
        for (int dc = 0; dc < 8; dc++) {
#pragma unroll
            for (int kk = 0; kk < 2; kk++) {
                bf16x8 bv = *(const bf16x8*)&Vt[(dc * 16 + m) * VT_STR + kk * 32 + g * 8];
                o[dc] = __builtin_amdgcn_mfma_f32_16x16x32_bf16(ap[kk], bv, o[dc], 0, 0, 0);
            }
        }
    }

    // ---- epilogue: normalize, write y bf16 [B, L, H, HD] ----
    const int b = bh / NH;
    const int h = bh % NH;
#pragma unroll
    for (int r = 0; r < 4; r++) {
        const float inv = 1.f / lsum[r];
        const int lrow = q0 + w * 16 + g * 4 + r;
        unsigned short* dst = y + (((size_t)b * LSEQ + lrow) * NH + h) * HD;
#pragma unroll
        for (int dc = 0; dc < 8; dc++)
            dst[dc * 16 + m] = f2bf(o[dc][r] * inv);
    }
}

// ---------------------------------------------------------------------------
extern "C" void kernel_launch(void* const* d_in, const int* in_sizes, int n_in,
                              void* d_out, int out_size, void* d_ws, size_t ws_size,
                              hipStream_t stream) {
    const float* x      = (const float*)d_in[0];
    const float* rope   = (const float*)d_in[1];
    const float* w_attn = (const float*)d_in[2];
    const float* w_proj = (const float*)d_in[3];
    float* out = (float*)d_out;
    unsigned short* ws = (unsigned short*)d_ws;

    const size_t per = (size_t)BATCH * NH * LSEQ * HD;  // 8,388,608
    unsigned short* qb  = ws;
    unsigned short* kb  = ws + per;
    unsigned short* vb  = ws + 2 * per;
    unsigned short* yb  = ws + 3 * per;
    unsigned short* xb  = ws + 4 * per;
    unsigned short* wab = xb + (size_t)N1;
    unsigned short* wpb = wab + (size_t)N2;

    const int M = BATCH * LSEQ;  // 4096

    // 0) cast inputs to bf16
    const int cast_blocks = (N1 + N2 + N3) / 4 / 256;  // 24576
    cast_bf16_kernel<<<cast_blocks, 256, 0, stream>>>(x, w_attn, w_proj, xb, wab, wpb);

    // 1) QKV projection (MFMA bf16), scatter into [B,H,L,HD] bf16
    dim3 g1(3 * EMB / 128, M / 128);  // (48, 32)
    gemm_bt_bf16<<<g1, 256, 0, stream>>>(xb, wab, nullptr, qb, kb, vb, M, 3 * EMB, EMB, 1);

    // 2) RoPE in-place on bf16 q, k
    rope_kernel<<<2 * NT8 / 256, 256, 0, stream>>>(qb, kb, rope);

    // 3) causal flash attention (MFMA bf16) -> y bf16 [B,L,H,HD]
    dim3 ga(LSEQ / TQ, BATCH * NH);  // (32, 32)
    attn_kernel<<<ga, 256, 0, stream>>>(qb, kb, vb, yb);

    // 4) output projection (MFMA bf16) -> fp32 out
    dim3 g2(EMB / 128, M / 128);  // (16, 32)
    gemm_bt_bf16<<<g2, 256, 0, stream>>>(yb, wpb, out, nullptr, nullptr, nullptr, M, EMB, EMB, 0);
}